// Round 4
// baseline (502.953 us; speedup 1.0000x reference)
//
#include <hip/hip_runtime.h>

// Problem constants (fixed by setup_inputs: B=32, N=1024, D=1024, K=512).
constexpr int Bb = 32;
constexpr int Nn = 1024;
constexpr int Dd = 1024;
constexpr int Kk = 512;            // updated rows per batch
constexpr int Mm = Bb * Kk;        // 16384 GEMM rows
constexpr int KD = 2 * Dd;         // 2048 fused K-dim ([h|w] x [U|V]^T)
constexpr int NT = KD / 64;        // 32 K-tiles of BK=64

using bf16x8 = __bf16 __attribute__((ext_vector_type(8)));
using f32x4  = float __attribute__((ext_vector_type(4)));

// ---------------------------------------------------------------------------
// Workspace layout (~68.3 MB):
//   [0, 64 MiB)    Abf : bf16 [16384][2048] = gathered [h | w] rows
//   +64 MiB        Bbf : bf16 [1024][2048]  = [U | V] rows        (4 MiB)
//   then g[16384], sW[32][1024], rownorm[16384], mask[1024], cnt[64]
// ---------------------------------------------------------------------------
constexpr size_t WS_ABF  = 0;
constexpr size_t WS_BBF  = (size_t)Mm * KD * 2;
constexpr size_t WS_G    = WS_BBF + (size_t)Nn * KD * 2;
constexpr size_t WS_SW   = WS_G + Mm * sizeof(float);
constexpr size_t WS_RN   = WS_SW + Bb * Nn * sizeof(float);
constexpr size_t WS_MASK = WS_RN + Mm * sizeof(float);
constexpr size_t WS_CNT  = WS_MASK + Nn * sizeof(int);

// ---------------------------------------------------------------------------
// Fused setup kernel (one launch):
//   blocks [0,1024)      : pack [U|V] -> bf16 Bbf
//   blocks [1024,1280)   : sW[b][e] = s[b,:].W[e,:]
//   block  1280          : mask[n] = k+1 iff idx[k]==n
//   blocks [1281,1297)   : zero rownorm; block 1281 also zeros cnt
// ---------------------------------------------------------------------------
__global__ __launch_bounds__(256)
void setup_kernel(const float* __restrict__ U, const float* __restrict__ V,
                  const float* __restrict__ W, const float* __restrict__ s,
                  const int* __restrict__ idx,
                  __bf16* __restrict__ Bbf, float* __restrict__ sW,
                  int* __restrict__ mask, float* __restrict__ rownorm,
                  int* __restrict__ cnt) {
  int blk = blockIdx.x, tid = threadIdx.x;
  if (blk < 1024) {                       // --- prep B
    int t = blk * 256 + tid;
    int e = t >> 8;
    int c = (t & 255) << 3;
    const float* src = (c < Dd) ? (U + (size_t)e * Dd + c)
                                : (V + (size_t)e * Dd + (c - Dd));
    f32x4 f0 = *(const f32x4*)src;
    f32x4 f1 = *(const f32x4*)(src + 4);
    bf16x8 v;
    v[0]=(__bf16)f0[0]; v[1]=(__bf16)f0[1]; v[2]=(__bf16)f0[2]; v[3]=(__bf16)f0[3];
    v[4]=(__bf16)f1[0]; v[5]=(__bf16)f1[1]; v[6]=(__bf16)f1[2]; v[7]=(__bf16)f1[3];
    *(bf16x8*)(Bbf + (size_t)e * KD + c) = v;
  } else if (blk < 1280) {                // --- sW
    int e = (blk - 1024) * 4 + (tid >> 6);
    int lane = tid & 63;
    const float* wp = W + (size_t)e * Dd;
    float wr[16];
#pragma unroll
    for (int c = 0; c < 4; c++) {
      f32x4 wv = *(const f32x4*)(wp + c * 256 + lane * 4);
      wr[c*4+0]=wv[0]; wr[c*4+1]=wv[1]; wr[c*4+2]=wv[2]; wr[c*4+3]=wv[3];
    }
    for (int b = 0; b < Bb; b++) {
      const float* sp = s + (size_t)b * Dd;
      float acc = 0.f;
#pragma unroll
      for (int c = 0; c < 4; c++) {
        f32x4 sv = *(const f32x4*)(sp + c * 256 + lane * 4);
        acc += sv[0]*wr[c*4+0] + sv[1]*wr[c*4+1] + sv[2]*wr[c*4+2] + sv[3]*wr[c*4+3];
      }
#pragma unroll
      for (int off = 32; off; off >>= 1) acc += __shfl_xor(acc, off);
      if (lane == 0) sW[b * Nn + e] = acc;
    }
  } else if (blk == 1280) {               // --- mask
#pragma unroll
    for (int q = 0; q < 4; q++) mask[tid * 4 + q] = 0;
    __syncthreads();
    mask[idx[tid]] = tid + 1;
    mask[idx[tid + 256]] = tid + 257;
  } else {                                // --- zero rownorm (+cnt)
    int base = (blk - 1281) * 1024 + tid * 4;
    *(f32x4*)(rownorm + base) = f32x4{0.f, 0.f, 0.f, 0.f};
    if (blk == 1281 && tid < 64) cnt[tid] = 0;
  }
}

// --- fused per-row kernel: copy non-updated rows; for updated rows pack
//     bf16 [h|w] into Abf AND compute g = sigmoid(s.(h+w)) in fp32.
__global__ __launch_bounds__(256)
void prep_rows_kernel(const float* __restrict__ s,
                      const float* __restrict__ hiddens,
                      const float* __restrict__ keys,
                      const int* __restrict__ mask,
                      __bf16* __restrict__ Abf,
                      float* __restrict__ g_out,
                      float* __restrict__ out) {
  __shared__ float red[4];
  int bid = blockIdx.x;                 // (b, n)
  int b = bid >> 10, n = bid & 1023;
  int tid = threadIdx.x;
  int mk = mask[n];
  const float* hp = hiddens + (size_t)bid * Dd;
  if (mk == 0) {                        // plain copy (uniform per block)
    ((f32x4*)(out + (size_t)bid * Dd))[tid] = ((const f32x4*)hp)[tid];
    return;
  }
  int m = b * Kk + (mk - 1);
  const float* src = (tid < 128) ? hp : (keys + (size_t)bid * Dd);
  int d = (tid & 127) * 8;
  const float* sp = s + (size_t)b * Dd + d;
  f32x4 x0 = *(const f32x4*)(src + d);
  f32x4 x1 = *(const f32x4*)(src + d + 4);
  f32x4 s0 = *(const f32x4*)sp;
  f32x4 s1 = *(const f32x4*)(sp + 4);
  float part = s0[0]*x0[0]+s0[1]*x0[1]+s0[2]*x0[2]+s0[3]*x0[3]
             + s1[0]*x1[0]+s1[1]*x1[1]+s1[2]*x1[2]+s1[3]*x1[3];
  bf16x8 v;
  v[0]=(__bf16)x0[0]; v[1]=(__bf16)x0[1]; v[2]=(__bf16)x0[2]; v[3]=(__bf16)x0[3];
  v[4]=(__bf16)x1[0]; v[5]=(__bf16)x1[1]; v[6]=(__bf16)x1[2]; v[7]=(__bf16)x1[3];
  *(bf16x8*)(Abf + (size_t)m * KD + (tid < 128 ? 0 : Dd) + d) = v;
#pragma unroll
  for (int off = 32; off; off >>= 1) part += __shfl_xor(part, off);
  if ((tid & 63) == 0) red[tid >> 6] = part;
  __syncthreads();
  if (tid == 0) {
    float acc = red[0] + red[1] + red[2] + red[3];
    g_out[m] = 1.f / (1.f + expf(-acc));
  }
}

// ---------------------------------------------------------------------------
// 256x256 8-phase GEMM, deep-prefetch schedule + fused row-normalize.
// All 4 halves of kt n+1 issued at P0(n) -> leads 3/3/4/5 phases.
// Waits (halves=2 loads each, oldest-first): P0 vmcnt(10), P1 vmcnt(8),
// P2 none, P3 vmcnt(4) [guarantees next iter's P0 ds_reads].
// Tail iter: vmcnt(2)/vmcnt(0).
// ---------------------------------------------------------------------------
#define VMW(N) asm volatile("s_waitcnt vmcnt(" #N ")" ::: "memory")
#define BAR()  __builtin_amdgcn_s_barrier()
#define PRI1() __builtin_amdgcn_s_setprio(1)
#define PRI0() __builtin_amdgcn_s_setprio(0)

#define STAGE_HALF(SRC, LDSOFF, BUF, HALF, KT)                                  \
  { _Pragma("unroll")                                                           \
    for (int i_ = 0; i_ < 2; ++i_) {                                            \
      __builtin_amdgcn_global_load_lds(                                         \
        (const __attribute__((address_space(1))) void*)                         \
            ((SRC) + (size_t)((HALF)*128 + i_*64)*4096 + (size_t)(KT)*128),     \
        (__attribute__((address_space(3))) void*)                               \
            (ldsc + (LDSOFF) + (BUF)*32768 + (HALF)*16384 + i_*8192 + t16),     \
        16, 0, 0);                                                              \
    } }

#define LDA4(D, BUF, RBASE)                                                     \
  { _Pragma("unroll")                                                           \
    for (int i_ = 0; i_ < 4; ++i_) {                                            \
      const char* p_ = ldsc + (BUF)*32768 + ((RBASE) + i_*16 + lr)*128;         \
      D[i_][0] = *(const bf16x8*)(p_ + kb0);                                    \
      D[i_][1] = *(const bf16x8*)(p_ + kb1);                                    \
    } }

#define LDB2(D, BUF, RBASE)                                                     \
  { _Pragma("unroll")                                                           \
    for (int j_ = 0; j_ < 2; ++j_) {                                            \
      const char* p_ = ldsc + 65536 + (BUF)*32768 + ((RBASE) + j_*16 + lr)*128; \
      D[j_][0] = *(const bf16x8*)(p_ + kb0);                                    \
      D[j_][1] = *(const bf16x8*)(p_ + kb1);                                    \
    } }

#define MF16(IOFF, JOFF, AF, BF)                                                \
  { _Pragma("unroll")                                                           \
    for (int i_ = 0; i_ < 4; ++i_)                                              \
      { _Pragma("unroll")                                                       \
        for (int j_ = 0; j_ < 2; ++j_)                                          \
          { _Pragma("unroll")                                                   \
            for (int k_ = 0; k_ < 2; ++k_)                                      \
              acc[(IOFF)+i_][(JOFF)+j_] =                                       \
                __builtin_amdgcn_mfma_f32_16x16x32_bf16(                        \
                  AF[i_][k_], BF[j_][k_], acc[(IOFF)+i_][(JOFF)+j_], 0, 0, 0);  \
          } } }

__global__ __launch_bounds__(512, 2)
void gemm_kernel(const __bf16* __restrict__ Abf,
                 const __bf16* __restrict__ Bbf,
                 const int* __restrict__ idx,
                 const float* __restrict__ sW,
                 const float* __restrict__ g,
                 const float* __restrict__ hiddens,
                 float* __restrict__ rownorm,
                 int* __restrict__ cnt,
                 float* __restrict__ out) {
  __shared__ __bf16 lds[65536];        // 128 KiB -> 1 block/CU, 256 blocks
  char* ldsc = (char*)lds;

  const int bid = blockIdx.x;
  // nt-major: the 4 nt-siblings of one mt share XCD (bid%8 == mt%8).
  const int mt = bid & 63, nt = bid >> 6;    // 64 M-tiles x 4 N-tiles
  const int m0 = mt * 256, e0 = nt * 256;
  const int tid = threadIdx.x;
  const int lane = tid & 63, wid = tid >> 6;
  const int wr = wid >> 2, wc = wid & 3;     // 2 x 4 wave grid, 128x64/wave
  const int lr = lane & 15, lg = lane >> 4;

  // staging: thread covers 16B at linear LDS dest t16; source col
  // pre-swizzled so linear gload_lds produces the swizzled LDS image.
  const int t16  = tid * 16;
  const int colb = t16 & 127;
  const int r_lo = t16 >> 7;                 // row within 8KB chunk (0..63)
  const int scol = colb ^ ((r_lo & 7) << 4);
  const char* Asrc = (const char*)Abf + (size_t)(m0 + r_lo) * 4096 + scol;
  const char* Bsrc = (const char*)Bbf + (size_t)(e0 + r_lo) * 4096 + scol;

  // ds_read swizzled k-offsets (row&7 == lr&7 for all frag rows)
  const int key = (lr & 7) << 4;
  const int kb0 = (lg * 16) ^ key;
  const int kb1 = (64 + lg * 16) ^ key;

  f32x4 acc[8][4] = {};
  bf16x8 aLo[4][2], aHi[4][2], bLo[2][2], bHi[2][2];

  // Prologue: stage kt0 (4 halves, 8 loads); force Ah0,Bh0 before loop.
  STAGE_HALF(Asrc, 0,     0, 0, 0);
  STAGE_HALF(Bsrc, 65536, 0, 0, 0);
  STAGE_HALF(Asrc, 0,     0, 1, 0);
  STAGE_HALF(Bsrc, 65536, 0, 1, 0);
  VMW(4);
  BAR();

  for (int n = 0; n < NT - 1; ++n) {
    const int buf = n & 1, sbuf = buf ^ 1;
    // P0: read Ah0+Bh0 frags; issue ALL 4 halves of kt n+1; deep wait.
    LDA4(aLo, buf, wr * 64);
    LDB2(bLo, buf, wc * 32);
    STAGE_HALF(Asrc, 0,     sbuf, 0, n + 1);
    STAGE_HALF(Bsrc, 65536, sbuf, 0, n + 1);
    STAGE_HALF(Asrc, 0,     sbuf, 1, n + 1);
    STAGE_HALF(Bsrc, 65536, sbuf, 1, n + 1);
    VMW(10); BAR(); PRI1(); MF16(0, 0, aLo, bLo); PRI0(); BAR();
    // P1
    LDA4(aHi, buf, wr * 64 + 128);
    VMW(8); BAR(); PRI1(); MF16(4, 0, aHi, bLo); PRI0(); BAR();
    // P2
    LDB2(bHi, buf, wc * 32 + 128);
    BAR(); PRI1(); MF16(0, 2, aLo, bHi); PRI0(); BAR();
    // P3: vmcnt(4) guarantees next iter's P0 ds_reads (Ah0',Bh0' landed).
    VMW(4); BAR(); PRI1(); MF16(4, 2, aHi, bHi); PRI0(); BAR();
  }
  // Tail kt (no staging): drain 2 -> 0.
  {
    const int buf = (NT - 1) & 1;
    LDA4(aLo, buf, wr * 64);
    LDB2(bLo, buf, wc * 32);
    VMW(2); BAR(); PRI1(); MF16(0, 0, aLo, bLo); PRI0(); BAR();
    LDA4(aHi, buf, wr * 64 + 128);
    VMW(0); BAR(); PRI1(); MF16(4, 0, aHi, bLo); PRI0(); BAR();
    LDB2(bHi, buf, wc * 32 + 128);
    BAR(); PRI1(); MF16(0, 2, aLo, bHi); PRI0(); BAR();
    PRI1(); MF16(4, 2, aHi, bHi); PRI0();
  }

  // Pass 1: h_new = h + g*relu(acc + sW) IN PLACE in acc; rownorm atomics.
  // C/D frag layout (m89): lane holds C[(lane>>4)*4 + r][lane&15].
#pragma unroll
  for (int i = 0; i < 8; ++i) {
    const int mrow = m0 + (i & 3) * 16 + wr * 64 + (i >> 2) * 128;
#pragma unroll
    for (int r = 0; r < 4; ++r) {
      int m = mrow + lg * 4 + r;
      int b = m >> 9;
      int rowidx = idx[m & (Kk - 1)];
      size_t base = ((size_t)(b * Nn + rowidx)) * Dd;
      float gg = g[m];
      float part = 0.f;
#pragma unroll
      for (int j = 0; j < 4; ++j) {
        int e = e0 + (j & 1) * 16 + wc * 32 + (j >> 1) * 128 + lr;
        float ht = acc[i][j][r] + sW[b * Nn + e];
        ht = fmaxf(ht, 0.f);
        float v = hiddens[base + e] + gg * ht;
        acc[i][j][r] = v;              // keep h_new in registers
        part += v * v;
      }
      part += __shfl_xor(part, 1);
      part += __shfl_xor(part, 2);
      part += __shfl_xor(part, 4);
      part += __shfl_xor(part, 8);
      if (lr == 0) atomicAdd(&rownorm[m], part);
    }
  }

  // Cross-block completion: 4 nt-siblings per mt, all co-resident (1 blk/CU).
  // __syncthreads drains vmcnt -> this block's atomics have completed.
  __syncthreads();
  if (tid == 0) {
    __threadfence();
    atomicAdd(&cnt[mt], 1);
    while (atomicAdd(&cnt[mt], 0) < 4) { }
  }
  __syncthreads();
  __threadfence();

  // Pass 2: y = rsqrt(max(rownorm,eps)) via atomic read; scale + store.
#pragma unroll
  for (int i = 0; i < 8; ++i) {
    const int mrow = m0 + (i & 3) * 16 + wr * 64 + (i >> 2) * 128;
#pragma unroll
    for (int r = 0; r < 4; ++r) {
      int m = mrow + lg * 4 + r;
      int b = m >> 9;
      int rowidx = idx[m & (Kk - 1)];
      size_t base = ((size_t)(b * Nn + rowidx)) * Dd;
      float nr = 0.f;
      if (lr == 0) nr = atomicAdd(&rownorm[m], 0.0f);   // coherent read
      nr = __shfl(nr, lg * 16);
      nr = fmaxf(nr, 1e-12f);
      float y = rsqrtf(nr);
      y = y * (1.5f - 0.5f * nr * y * y);               // Newton step
#pragma unroll
      for (int j = 0; j < 4; ++j) {
        int e = e0 + (j & 1) * 16 + wc * 32 + (j >> 1) * 128 + lr;
        out[base + e] = acc[i][j][r] * y;
      }
    }
  }
}

extern "C" void kernel_launch(void* const* d_in, const int* in_sizes, int n_in,
                              void* d_out, int out_size, void* d_ws, size_t ws_size,
                              hipStream_t stream) {
  const float* s       = (const float*)d_in[0];
  const float* hiddens = (const float*)d_in[1];
  const float* keys    = (const float*)d_in[2];
  const float* U       = (const float*)d_in[3];
  const float* V       = (const float*)d_in[4];
  const float* W       = (const float*)d_in[5];
  const int*   idx     = (const int*)d_in[6];
  float* out = (float*)d_out;

  char* ws = (char*)d_ws;
  __bf16* Abf   = (__bf16*)(ws + WS_ABF);
  __bf16* Bbf   = (__bf16*)(ws + WS_BBF);
  float*  g     = (float*)(ws + WS_G);
  float*  sW    = (float*)(ws + WS_SW);
  float*  rnorm = (float*)(ws + WS_RN);
  int*    mask  = (int*)(ws + WS_MASK);
  int*    cnt   = (int*)(ws + WS_CNT);

  setup_kernel<<<1297, 256, 0, stream>>>(U, V, W, s, idx, Bbf, sW, mask, rnorm, cnt);
  prep_rows_kernel<<<Bb * Nn, 256, 0, stream>>>(s, hiddens, keys, mask, Abf, g, out);
  gemm_kernel<<<(Mm / 256) * (Nn / 256), 512, 0, stream>>>(
      Abf, Bbf, idx, sW, g, hiddens, rnorm, cnt, out);
}

// Round 5
// 483.347 us; speedup vs baseline: 1.0406x; 1.0406x over previous
//
#include <hip/hip_runtime.h>

// Problem constants (fixed by setup_inputs: B=32, N=1024, D=1024, K=512).
constexpr int Bb = 32;
constexpr int Nn = 1024;
constexpr int Dd = 1024;
constexpr int Kk = 512;            // updated rows per batch
constexpr int Mm = Bb * Kk;        // 16384 GEMM rows
constexpr int KD = 2 * Dd;         // 2048 fused K-dim ([h|w] x [U|V]^T)
constexpr int NT = KD / 64;        // 32 K-tiles of BK=64

using bf16x8 = __bf16 __attribute__((ext_vector_type(8)));
using f32x4  = float __attribute__((ext_vector_type(4)));

// ---------------------------------------------------------------------------
// Workspace layout (~68.3 MB):
//   [0, 64 MiB)    Abf : bf16 [16384][2048] = gathered [h | w] rows
//   +64 MiB        Bbf : bf16 [1024][2048]  = [U | V] rows        (4 MiB)
//   then g[16384], sW[32][1024], rownorm[16384], mask[1024]
// ---------------------------------------------------------------------------
constexpr size_t WS_ABF  = 0;
constexpr size_t WS_BBF  = (size_t)Mm * KD * 2;
constexpr size_t WS_G    = WS_BBF + (size_t)Nn * KD * 2;
constexpr size_t WS_SW   = WS_G + Mm * sizeof(float);
constexpr size_t WS_RN   = WS_SW + Bb * Nn * sizeof(float);
constexpr size_t WS_MASK = WS_RN + Mm * sizeof(float);

// ---------------------------------------------------------------------------
// Fused setup kernel (one launch):
//   blocks [0,1024)      : pack [U|V] -> bf16 Bbf
//   blocks [1024,1280)   : sW[b][e] = s[b,:].W[e,:]
//   block  1280          : mask[n] = k+1 iff idx[k]==n
//   blocks [1281,1297)   : zero rownorm
// ---------------------------------------------------------------------------
__global__ __launch_bounds__(256)
void setup_kernel(const float* __restrict__ U, const float* __restrict__ V,
                  const float* __restrict__ W, const float* __restrict__ s,
                  const int* __restrict__ idx,
                  __bf16* __restrict__ Bbf, float* __restrict__ sW,
                  int* __restrict__ mask, float* __restrict__ rownorm) {
  int blk = blockIdx.x, tid = threadIdx.x;
  if (blk < 1024) {                       // --- prep B
    int t = blk * 256 + tid;
    int e = t >> 8;
    int c = (t & 255) << 3;
    const float* src = (c < Dd) ? (U + (size_t)e * Dd + c)
                                : (V + (size_t)e * Dd + (c - Dd));
    f32x4 f0 = *(const f32x4*)src;
    f32x4 f1 = *(const f32x4*)(src + 4);
    bf16x8 v;
    v[0]=(__bf16)f0[0]; v[1]=(__bf16)f0[1]; v[2]=(__bf16)f0[2]; v[3]=(__bf16)f0[3];
    v[4]=(__bf16)f1[0]; v[5]=(__bf16)f1[1]; v[6]=(__bf16)f1[2]; v[7]=(__bf16)f1[3];
    *(bf16x8*)(Bbf + (size_t)e * KD + c) = v;
  } else if (blk < 1280) {                // --- sW
    int e = (blk - 1024) * 4 + (tid >> 6);
    int lane = tid & 63;
    const float* wp = W + (size_t)e * Dd;
    float wr[16];
#pragma unroll
    for (int c = 0; c < 4; c++) {
      f32x4 wv = *(const f32x4*)(wp + c * 256 + lane * 4);
      wr[c*4+0]=wv[0]; wr[c*4+1]=wv[1]; wr[c*4+2]=wv[2]; wr[c*4+3]=wv[3];
    }
    for (int b = 0; b < Bb; b++) {
      const float* sp = s + (size_t)b * Dd;
      float acc = 0.f;
#pragma unroll
      for (int c = 0; c < 4; c++) {
        f32x4 sv = *(const f32x4*)(sp + c * 256 + lane * 4);
        acc += sv[0]*wr[c*4+0] + sv[1]*wr[c*4+1] + sv[2]*wr[c*4+2] + sv[3]*wr[c*4+3];
      }
#pragma unroll
      for (int off = 32; off; off >>= 1) acc += __shfl_xor(acc, off);
      if (lane == 0) sW[b * Nn + e] = acc;
    }
  } else if (blk == 1280) {               // --- mask
#pragma unroll
    for (int q = 0; q < 4; q++) mask[tid * 4 + q] = 0;
    __syncthreads();
    mask[idx[tid]] = tid + 1;
    mask[idx[tid + 256]] = tid + 257;
  } else {                                // --- zero rownorm
    int base = (blk - 1281) * 1024 + tid * 4;
    *(f32x4*)(rownorm + base) = f32x4{0.f, 0.f, 0.f, 0.f};
  }
}

// --- fused per-row kernel: copy non-updated rows; for updated rows pack
//     bf16 [h|w] into Abf AND compute g = sigmoid(s.(h+w)) in fp32.
__global__ __launch_bounds__(256)
void prep_rows_kernel(const float* __restrict__ s,
                      const float* __restrict__ hiddens,
                      const float* __restrict__ keys,
                      const int* __restrict__ mask,
                      __bf16* __restrict__ Abf,
                      float* __restrict__ g_out,
                      float* __restrict__ out) {
  __shared__ float red[4];
  int bid = blockIdx.x;                 // (b, n)
  int b = bid >> 10, n = bid & 1023;
  int tid = threadIdx.x;
  int mk = mask[n];
  const float* hp = hiddens + (size_t)bid * Dd;
  if (mk == 0) {                        // plain copy (uniform per block)
    ((f32x4*)(out + (size_t)bid * Dd))[tid] = ((const f32x4*)hp)[tid];
    return;
  }
  int m = b * Kk + (mk - 1);
  const float* src = (tid < 128) ? hp : (keys + (size_t)bid * Dd);
  int d = (tid & 127) * 8;
  const float* sp = s + (size_t)b * Dd + d;
  f32x4 x0 = *(const f32x4*)(src + d);
  f32x4 x1 = *(const f32x4*)(src + d + 4);
  f32x4 s0 = *(const f32x4*)sp;
  f32x4 s1 = *(const f32x4*)(sp + 4);
  float part = s0[0]*x0[0]+s0[1]*x0[1]+s0[2]*x0[2]+s0[3]*x0[3]
             + s1[0]*x1[0]+s1[1]*x1[1]+s1[2]*x1[2]+s1[3]*x1[3];
  bf16x8 v;
  v[0]=(__bf16)x0[0]; v[1]=(__bf16)x0[1]; v[2]=(__bf16)x0[2]; v[3]=(__bf16)x0[3];
  v[4]=(__bf16)x1[0]; v[5]=(__bf16)x1[1]; v[6]=(__bf16)x1[2]; v[7]=(__bf16)x1[3];
  *(bf16x8*)(Abf + (size_t)m * KD + (tid < 128 ? 0 : Dd) + d) = v;
#pragma unroll
  for (int off = 32; off; off >>= 1) part += __shfl_xor(part, off);
  if ((tid & 63) == 0) red[tid >> 6] = part;
  __syncthreads();
  if (tid == 0) {
    float acc = red[0] + red[1] + red[2] + red[3];
    g_out[m] = 1.f / (1.f + expf(-acc));
  }
}

// ---------------------------------------------------------------------------
// 256x256 8-phase GEMM, deep-prefetch schedule (R4 K-loop, verified by
// per-wave vmcnt counting; 3-5 phases of latency slack per staged half).
// Epilogue: write h_new + atomic rownorm (R3 style — fused norm regressed).
// ---------------------------------------------------------------------------
#define VMW(N) asm volatile("s_waitcnt vmcnt(" #N ")" ::: "memory")
#define BAR()  __builtin_amdgcn_s_barrier()
#define PRI1() __builtin_amdgcn_s_setprio(1)
#define PRI0() __builtin_amdgcn_s_setprio(0)

#define STAGE_HALF(SRC, LDSOFF, BUF, HALF, KT)                                  \
  { _Pragma("unroll")                                                           \
    for (int i_ = 0; i_ < 2; ++i_) {                                            \
      __builtin_amdgcn_global_load_lds(                                         \
        (const __attribute__((address_space(1))) void*)                         \
            ((SRC) + (size_t)((HALF)*128 + i_*64)*4096 + (size_t)(KT)*128),     \
        (__attribute__((address_space(3))) void*)                               \
            (ldsc + (LDSOFF) + (BUF)*32768 + (HALF)*16384 + i_*8192 + t16),     \
        16, 0, 0);                                                              \
    } }

#define LDA4(D, BUF, RBASE)                                                     \
  { _Pragma("unroll")                                                           \
    for (int i_ = 0; i_ < 4; ++i_) {                                            \
      const char* p_ = ldsc + (BUF)*32768 + ((RBASE) + i_*16 + lr)*128;         \
      D[i_][0] = *(const bf16x8*)(p_ + kb0);                                    \
      D[i_][1] = *(const bf16x8*)(p_ + kb1);                                    \
    } }

#define LDB2(D, BUF, RBASE)                                                     \
  { _Pragma("unroll")                                                           \
    for (int j_ = 0; j_ < 2; ++j_) {                                            \
      const char* p_ = ldsc + 65536 + (BUF)*32768 + ((RBASE) + j_*16 + lr)*128; \
      D[j_][0] = *(const bf16x8*)(p_ + kb0);                                    \
      D[j_][1] = *(const bf16x8*)(p_ + kb1);                                    \
    } }

#define MF16(IOFF, JOFF, AF, BF)                                                \
  { _Pragma("unroll")                                                           \
    for (int i_ = 0; i_ < 4; ++i_)                                              \
      { _Pragma("unroll")                                                       \
        for (int j_ = 0; j_ < 2; ++j_)                                          \
          { _Pragma("unroll")                                                   \
            for (int k_ = 0; k_ < 2; ++k_)                                      \
              acc[(IOFF)+i_][(JOFF)+j_] =                                       \
                __builtin_amdgcn_mfma_f32_16x16x32_bf16(                        \
                  AF[i_][k_], BF[j_][k_], acc[(IOFF)+i_][(JOFF)+j_], 0, 0, 0);  \
          } } }

__global__ __launch_bounds__(512, 2)
void gemm_kernel(const __bf16* __restrict__ Abf,
                 const __bf16* __restrict__ Bbf,
                 const int* __restrict__ idx,
                 const float* __restrict__ sW,
                 const float* __restrict__ g,
                 const float* __restrict__ hiddens,
                 float* __restrict__ rownorm,
                 float* __restrict__ out) {
  __shared__ __bf16 lds[65536];        // 128 KiB -> 1 block/CU, 256 blocks
  char* ldsc = (char*)lds;

  const int bid = blockIdx.x;
  // nt-major: the 4 nt-siblings of one mt share XCD (bid%8 == mt%8).
  const int mt = bid & 63, nt = bid >> 6;    // 64 M-tiles x 4 N-tiles
  const int m0 = mt * 256, e0 = nt * 256;
  const int tid = threadIdx.x;
  const int lane = tid & 63, wid = tid >> 6;
  const int wr = wid >> 2, wc = wid & 3;     // 2 x 4 wave grid, 128x64/wave
  const int lr = lane & 15, lg = lane >> 4;

  // staging: thread covers 16B at linear LDS dest t16; source col
  // pre-swizzled so linear gload_lds produces the swizzled LDS image.
  const int t16  = tid * 16;
  const int colb = t16 & 127;
  const int r_lo = t16 >> 7;                 // row within 8KB chunk (0..63)
  const int scol = colb ^ ((r_lo & 7) << 4);
  const char* Asrc = (const char*)Abf + (size_t)(m0 + r_lo) * 4096 + scol;
  const char* Bsrc = (const char*)Bbf + (size_t)(e0 + r_lo) * 4096 + scol;

  // ds_read swizzled k-offsets (row&7 == lr&7 for all frag rows)
  const int key = (lr & 7) << 4;
  const int kb0 = (lg * 16) ^ key;
  const int kb1 = (64 + lg * 16) ^ key;

  f32x4 acc[8][4] = {};
  bf16x8 aLo[4][2], aHi[4][2], bLo[2][2], bHi[2][2];

  // Prologue: stage kt0 (4 halves, 8 loads); force Ah0,Bh0 before loop.
  STAGE_HALF(Asrc, 0,     0, 0, 0);
  STAGE_HALF(Bsrc, 65536, 0, 0, 0);
  STAGE_HALF(Asrc, 0,     0, 1, 0);
  STAGE_HALF(Bsrc, 65536, 0, 1, 0);
  VMW(4);
  BAR();

  for (int n = 0; n < NT - 1; ++n) {
    const int buf = n & 1, sbuf = buf ^ 1;
    // P0: read Ah0+Bh0 frags; issue ALL 4 halves of kt n+1; deep wait.
    LDA4(aLo, buf, wr * 64);
    LDB2(bLo, buf, wc * 32);
    STAGE_HALF(Asrc, 0,     sbuf, 0, n + 1);
    STAGE_HALF(Bsrc, 65536, sbuf, 0, n + 1);
    STAGE_HALF(Asrc, 0,     sbuf, 1, n + 1);
    STAGE_HALF(Bsrc, 65536, sbuf, 1, n + 1);
    VMW(10); BAR(); PRI1(); MF16(0, 0, aLo, bLo); PRI0(); BAR();
    // P1
    LDA4(aHi, buf, wr * 64 + 128);
    VMW(8); BAR(); PRI1(); MF16(4, 0, aHi, bLo); PRI0(); BAR();
    // P2
    LDB2(bHi, buf, wc * 32 + 128);
    BAR(); PRI1(); MF16(0, 2, aLo, bHi); PRI0(); BAR();
    // P3: vmcnt(4) guarantees next iter's P0 ds_reads (Ah0',Bh0' landed).
    VMW(4); BAR(); PRI1(); MF16(4, 2, aHi, bHi); PRI0(); BAR();
  }
  // Tail kt (no staging): drain 2 -> 0.
  {
    const int buf = (NT - 1) & 1;
    LDA4(aLo, buf, wr * 64);
    LDB2(bLo, buf, wc * 32);
    VMW(2); BAR(); PRI1(); MF16(0, 0, aLo, bLo); PRI0(); BAR();
    LDA4(aHi, buf, wr * 64 + 128);
    VMW(0); BAR(); PRI1(); MF16(4, 0, aHi, bLo); PRI0(); BAR();
    LDB2(bHi, buf, wc * 32 + 128);
    BAR(); PRI1(); MF16(0, 2, aLo, bHi); PRI0(); BAR();
    PRI1(); MF16(4, 2, aHi, bHi); PRI0();
  }

  // Epilogue: bias + relu + gate + residual + scatter + norm partials.
  // C/D frag layout (m89): lane holds C[(lane>>4)*4 + r][lane&15].
#pragma unroll
  for (int i = 0; i < 8; ++i) {
    const int mrow = m0 + (i & 3) * 16 + wr * 64 + (i >> 2) * 128;
#pragma unroll
    for (int r = 0; r < 4; ++r) {
      int m = mrow + lg * 4 + r;
      int b = m >> 9;
      int rowidx = idx[m & (Kk - 1)];
      size_t base = ((size_t)(b * Nn + rowidx)) * Dd;
      float gg = g[m];
      float part = 0.f;
#pragma unroll
      for (int j = 0; j < 4; ++j) {
        int e = e0 + (j & 1) * 16 + wc * 32 + (j >> 1) * 128 + lr;
        float ht = acc[i][j][r] + sW[b * Nn + e];
        ht = fmaxf(ht, 0.f);
        float v = hiddens[base + e] + gg * ht;
        out[base + e] = v;
        part += v * v;
      }
      part += __shfl_xor(part, 1);
      part += __shfl_xor(part, 2);
      part += __shfl_xor(part, 4);
      part += __shfl_xor(part, 8);
      if (lr == 0) atomicAdd(&rownorm[m], part);
    }
  }
}

// --- rescale updated rows by rsqrt(max(rownorm, eps)); one block per row
__global__ void norm_kernel(const int* __restrict__ idx,
                            const float* __restrict__ rownorm,
                            float* __restrict__ out) {
  int m = blockIdx.x;
  int b = m >> 9;
  int rowidx = idx[m & (Kk - 1)];
  float nr = fmaxf(rownorm[m], 1e-12f);
  float y = rsqrtf(nr);
  y = y * (1.5f - 0.5f * nr * y * y);   // Newton step for fp32 accuracy
  f32x4* p = (f32x4*)(out + ((size_t)(b * Nn + rowidx)) * Dd);
  f32x4 v = p[threadIdx.x];
  v[0] *= y; v[1] *= y; v[2] *= y; v[3] *= y;
  p[threadIdx.x] = v;
}

extern "C" void kernel_launch(void* const* d_in, const int* in_sizes, int n_in,
                              void* d_out, int out_size, void* d_ws, size_t ws_size,
                              hipStream_t stream) {
  const float* s       = (const float*)d_in[0];
  const float* hiddens = (const float*)d_in[1];
  const float* keys    = (const float*)d_in[2];
  const float* U       = (const float*)d_in[3];
  const float* V       = (const float*)d_in[4];
  const float* W       = (const float*)d_in[5];
  const int*   idx     = (const int*)d_in[6];
  float* out = (float*)d_out;

  char* ws = (char*)d_ws;
  __bf16* Abf   = (__bf16*)(ws + WS_ABF);
  __bf16* Bbf   = (__bf16*)(ws + WS_BBF);
  float*  g     = (float*)(ws + WS_G);
  float*  sW    = (float*)(ws + WS_SW);
  float*  rnorm = (float*)(ws + WS_RN);
  int*    mask  = (int*)(ws + WS_MASK);

  setup_kernel<<<1297, 256, 0, stream>>>(U, V, W, s, idx, Bbf, sW, mask, rnorm);
  prep_rows_kernel<<<Bb * Nn, 256, 0, stream>>>(s, hiddens, keys, mask, Abf, g, out);
  gemm_kernel<<<(Mm / 256) * (Nn / 256), 512, 0, stream>>>(
      Abf, Bbf, idx, sW, g, hiddens, rnorm, out);
  norm_kernel<<<Mm, 256, 0, stream>>>(idx, rnorm, out);
}